// Round 8
// baseline (14.998 us; speedup 1.0000x reference)
//
#include <hip/hip_runtime.h>

// out[b,i,d] = 31 * sum_n tgt[b,i,n,d]   (softmax column-sums == 1, F-1 = 31)
// tgt [16, 32, 64, 512] fp32 -> out [16, 32, 512] fp32. 67 MB read, 1 MB write.
//
// R7: TLP curve continues. 1024 blocks (4/CU, 4 waves/SIMD), 16 NT loads
// per thread (total outstanding/SIMD constant vs R6). Wave layout:
// 16 float4 cols x 4 n-quarters per wave; combine quarters with two
// in-wave __shfl_xor (16, 32). Still zero LDS / zero barriers.

typedef float f32x4 __attribute__((ext_vector_type(4)));

__global__ __launch_bounds__(256) void rffr_colsum_kernel(
    const f32x4* __restrict__ tgt, f32x4* __restrict__ out) {
    const int bid  = blockIdx.x;              // 0..1023
    const int row  = bid >> 1;                // 0..511
    const int half = bid & 1;                 // col half (64 float4)
    const int tid  = threadIdx.x;             // 0..255
    const int wave = tid >> 6;                // 0..3 -> 16-col chunk
    const int lane = tid & 63;
    const int c    = half * 64 + wave * 16 + (lane & 15);  // float4 col
    const int q    = lane >> 4;               // n-quarter (16 n each)

    const f32x4* base = tgt + (size_t)row * 64 * 128
                            + (size_t)(q * 16) * 128 + c;

    f32x4 acc = (f32x4)(0.f);
#pragma unroll
    for (int k = 0; k < 16; ++k) {
        acc += __builtin_nontemporal_load(base + (size_t)k * 128);
    }

    // Combine the 4 n-quarters in-wave (lanes differ in bits 4,5).
    f32x4 o;
    o.x = __shfl_xor(acc.x, 16, 64);
    o.y = __shfl_xor(acc.y, 16, 64);
    o.z = __shfl_xor(acc.z, 16, 64);
    o.w = __shfl_xor(acc.w, 16, 64);
    acc += o;
    o.x = __shfl_xor(acc.x, 32, 64);
    o.y = __shfl_xor(acc.y, 32, 64);
    o.z = __shfl_xor(acc.z, 32, 64);
    o.w = __shfl_xor(acc.w, 32, 64);
    acc += o;

    if (q == 0) {
        f32x4 r = 31.0f * acc;
        __builtin_nontemporal_store(r, out + (size_t)row * 128 + c);
    }
}

extern "C" void kernel_launch(void* const* d_in, const int* in_sizes, int n_in,
                              void* d_out, int out_size, void* d_ws, size_t ws_size,
                              hipStream_t stream) {
    const f32x4* tgt = (const f32x4*)d_in[0];
    f32x4* out = (f32x4*)d_out;
    rffr_colsum_kernel<<<dim3(1024), dim3(256), 0, stream>>>(tgt, out);
}

// Round 9
// 13.496 us; speedup vs baseline: 1.1114x; 1.1114x over previous
//
#include <hip/hip_runtime.h>

// out[b,i,d] = 31 * sum_n tgt[b,i,n,d]   (softmax column-sums == 1, F-1 = 31)
// tgt [16, 32, 64, 512] fp32 -> out [16, 32, 512] fp32. 67 MB read, 1 MB write.
//
// R8: combine the winners — 1KB-contiguous segments (R4) + 2 waves/SIMD (R6).
// Block = row, 4 waves. Wave w owns n in [16w, 16w+16) for ALL 128 cols:
// each load instr = 64 consecutive float4 = one aligned 1KB segment.
// 32 NT loads/thread. Light tail: one ds_write_b128 + 1 barrier + 4
// ds_read_b128 per output (vs R2's 3-barrier tree).

typedef float f32x4 __attribute__((ext_vector_type(4)));

__global__ __launch_bounds__(256, 2) void rffr_colsum_kernel(
    const f32x4* __restrict__ tgt, f32x4* __restrict__ out) {
    const int row  = blockIdx.x;              // 0..511
    const int tid  = threadIdx.x;             // 0..255
    const int wave = tid >> 6;                // 0..3 -> n-range [16w,16w+16)
    const int lane = tid & 63;

    // acc0: cols [0,64), acc1: cols [64,128); col = lane (+64).
    const f32x4* base = tgt + (size_t)row * 64 * 128
                            + (size_t)(wave * 16) * 128 + lane;

    f32x4 a0 = (f32x4)(0.f);
    f32x4 a1 = (f32x4)(0.f);
#pragma unroll
    for (int k = 0; k < 16; ++k) {
        a0 += __builtin_nontemporal_load(base + (size_t)k * 128);
        a1 += __builtin_nontemporal_load(base + (size_t)k * 128 + 64);
    }

    __shared__ f32x4 part[4][128];
    part[wave][lane]      = a0;
    part[wave][lane + 64] = a1;
    __syncthreads();

    // 128 threads produce the 128 output float4 for this row.
    if (tid < 128) {
        f32x4 s = part[0][tid] + part[1][tid] + part[2][tid] + part[3][tid];
        f32x4 r = 31.0f * s;
        __builtin_nontemporal_store(r, out + (size_t)row * 128 + tid);
    }
}

extern "C" void kernel_launch(void* const* d_in, const int* in_sizes, int n_in,
                              void* d_out, int out_size, void* d_ws, size_t ws_size,
                              hipStream_t stream) {
    const f32x4* tgt = (const f32x4*)d_in[0];
    f32x4* out = (f32x4*)d_out;
    rffr_colsum_kernel<<<dim3(512), dim3(256), 0, stream>>>(tgt, out);
}

// Round 10
// 13.272 us; speedup vs baseline: 1.1300x; 1.0168x over previous
//
#include <hip/hip_runtime.h>

// out[b,i,d] = 31 * sum_n tgt[b,i,n,d]   (softmax column-sums == 1, F-1 = 31)
// tgt [16, 32, 64, 512] fp32 -> out [16, 32, 512] fp32. 67 MB read, 1 MB write.
//
// R9 = R6 revert (best measured variant, 13.25 us, 5.15 TB/s effective).
// 512 blocks (= rows), 2 waves/SIMD. Each wave: 32 float4 cols x 2 n-halves
// (lane>>5). 32 NT loads/thread fully unrolled; cross-half combine = 4
// in-wave __shfl_xor; no LDS, no barriers. Residual ~3 us over the
// 6.9 TB/s memset arithmetic is fixed replay/launch/service overhead —
// invariant across TLP/ILP/segment/cache-hint/tail axes (R0-R8).

typedef float f32x4 __attribute__((ext_vector_type(4)));

__global__ __launch_bounds__(256) void rffr_colsum_kernel(
    const f32x4* __restrict__ tgt, f32x4* __restrict__ out) {
    const int row  = blockIdx.x;              // 0..511
    const int tid  = threadIdx.x;             // 0..255
    const int wave = tid >> 6;                // 0..3 -> 32-col chunk
    const int lane = tid & 63;
    const int c    = (wave << 5) | (lane & 31);  // float4 col 0..127
    const int h    = lane >> 5;               // n-half: 0 -> n<32, 1 -> n>=32

    const f32x4* base = tgt + (size_t)row * 64 * 128 + (size_t)(h * 32) * 128 + c;

    f32x4 acc = (f32x4)(0.f);
#pragma unroll
    for (int k = 0; k < 32; ++k) {
        acc += __builtin_nontemporal_load(base + (size_t)k * 128);
    }

    // Exchange halves within the wave (lane ^ 32) and combine.
    f32x4 o;
    o.x = __shfl_xor(acc.x, 32, 64);
    o.y = __shfl_xor(acc.y, 32, 64);
    o.z = __shfl_xor(acc.z, 32, 64);
    o.w = __shfl_xor(acc.w, 32, 64);
    acc += o;

    if (h == 0) {
        f32x4 r = 31.0f * acc;
        __builtin_nontemporal_store(r, out + (size_t)row * 128 + c);
    }
}

extern "C" void kernel_launch(void* const* d_in, const int* in_sizes, int n_in,
                              void* d_out, int out_size, void* d_ws, size_t ws_size,
                              hipStream_t stream) {
    const f32x4* tgt = (const f32x4*)d_in[0];
    f32x4* out = (f32x4*)d_out;
    rffr_colsum_kernel<<<dim3(512), dim3(256), 0, stream>>>(tgt, out);
}